// Round 7
// baseline (131.277 us; speedup 1.0000x reference)
//
#include <hip/hip_runtime.h>
#include <math.h>

// Problem: B=64, N=1568, D=768, groups=8, rows/group=196, T=1568.
// Output (B, 393, 768) f32 = [cls row | 196 rows of group i0 | 196 rows of group i1].
//
// Reduction: top_k ranking depends only on t[b,g] = xn[b,g] . u,
// u = w1 @ (w2 @ (w3@w4)[0:384]).  (x_a term constant per batch; min-max
// normalization monotone.)  Output is then a pure gather of inp rows.
//
// Structure (3 graph nodes):
//   memset(counters) -> k_gemv_chain (64 blocks, 2 internal barriers)
//                    -> k_stream_gather (512 blocks, per-batch done[] release)

typedef float f32x4 __attribute__((ext_vector_type(4)));
typedef float f32x2 __attribute__((ext_vector_type(2)));

#define SCOPE_AGENT __HIP_MEMORY_SCOPE_AGENT

// ---------------- kernel 1: fused GEMV chain v -> p -> u ----------------
// 64 blocks x 256 threads (4 waves each; 256 waves total, co-resident on 256 CUs).
// bar[0], bar[1] are zeroed by the preceding memset each call.
__global__ __launch_bounds__(256) void k_gemv_chain(
    const float* __restrict__ w3, const float* __restrict__ w4,
    const float* __restrict__ w2, const float* __restrict__ w1,
    float* __restrict__ v, float* __restrict__ p, float* __restrict__ u,
    int* __restrict__ bar)
{
    const int tid = threadIdx.x;
    const int gw = blockIdx.x * 4 + (tid >> 6);   // global wave 0..255
    const int lane = tid & 63;

    // ---- stage 1: v[r] = w3[r, 0:768] . w4, r in [0, 384) ----
    {
        const f32x4* b4 = reinterpret_cast<const f32x4*>(w4);
        for (int r = gw; r < 384; r += 256) {
            const f32x4* a4 = reinterpret_cast<const f32x4*>(w3 + (size_t)r * 768);
            float s = 0.f;
#pragma unroll
            for (int i = 0; i < 3; ++i) {
                f32x4 a = a4[lane + 64 * i];
                f32x4 b = b4[lane + 64 * i];
                s += a.x * b.x + a.y * b.y + a.z * b.z + a.w * b.w;
            }
#pragma unroll
            for (int off = 32; off; off >>= 1) s += __shfl_down(s, off);
            if (lane == 0) v[r] = s;
        }
    }
    __syncthreads();
    if (tid == 0) {
        __hip_atomic_fetch_add(&bar[0], 1, __ATOMIC_ACQ_REL, SCOPE_AGENT);
        while (__hip_atomic_load(&bar[0], __ATOMIC_ACQUIRE, SCOPE_AGENT) < 64)
            __builtin_amdgcn_s_sleep(1);
    }
    __syncthreads();

    // ---- stage 2: p[r] = w2[r, 0:384] . v, r in [0, 768) ----
    {
        const f32x2* b2 = reinterpret_cast<const f32x2*>(v);
        for (int r = gw; r < 768; r += 256) {
            const f32x2* a2 = reinterpret_cast<const f32x2*>(w2 + (size_t)r * 384);
            float s = 0.f;
#pragma unroll
            for (int i = 0; i < 3; ++i) {
                f32x2 a = a2[lane + 64 * i];
                f32x2 b = b2[lane + 64 * i];
                s += a.x * b.x + a.y * b.y;
            }
#pragma unroll
            for (int off = 32; off; off >>= 1) s += __shfl_down(s, off);
            if (lane == 0) p[r] = s;
        }
    }
    __syncthreads();
    if (tid == 0) {
        __hip_atomic_fetch_add(&bar[1], 1, __ATOMIC_ACQ_REL, SCOPE_AGENT);
        while (__hip_atomic_load(&bar[1], __ATOMIC_ACQUIRE, SCOPE_AGENT) < 64)
            __builtin_amdgcn_s_sleep(1);
    }
    __syncthreads();

    // ---- stage 3: u[r] = w1[r, 0:768] . p, r in [0, 768) ----
    {
        const f32x4* b4 = reinterpret_cast<const f32x4*>(p);
        for (int r = gw; r < 768; r += 256) {
            const f32x4* a4 = reinterpret_cast<const f32x4*>(w1 + (size_t)r * 768);
            float s = 0.f;
#pragma unroll
            for (int i = 0; i < 3; ++i) {
                f32x4 a = a4[lane + 64 * i];
                f32x4 b = b4[lane + 64 * i];
                s += a.x * b.x + a.y * b.y + a.z * b.z + a.w * b.w;
            }
#pragma unroll
            for (int off = 32; off; off >>= 1) s += __shfl_down(s, off);
            if (lane == 0) u[r] = s;
        }
    }
}

// ---------------- kernel 2: fused max+LN+score -> per-batch gather ----------------
// 512 blocks x 768 threads, one (b,g) per block.  After writing t[b,g], block
// release-adds done[b]; spins until done[b]==8 (only its 7 siblings -> deadlock-
// free at any capacity; __launch_bounds__(768,6) additionally forces 2 blocks/CU
// so all 512 are co-resident).  Then gathers output chunk g of batch b.
__global__ __launch_bounds__(768, 6) void k_stream_gather(
    const float* __restrict__ x, const float* __restrict__ inp,
    const float* __restrict__ ln_w, const float* __restrict__ ln_b,
    const float* __restrict__ u, float* __restrict__ t,
    int* __restrict__ done, float* __restrict__ out)
{
    const int bg = blockIdx.x;            // 0..511
    const int b = bg >> 3;
    const int g = bg & 7;
    const int tid = threadIdx.x;          // 0..767
    const int col = tid % 192;            // float4 column
    const int chunk = tid / 192;          // 0..3, 49 rows each

    // hoist parameter loads above the streaming loop (L2-hot after k1)
    const float lw = ln_w[tid];
    const float lb = ln_b[tid];
    const float ud = u[tid];

    const f32x4* base = reinterpret_cast<const f32x4*>(
        x + ((size_t)b * 1568 + (size_t)g * 196 + (size_t)chunk * 49) * 768) + col;

    f32x4 mx = {-INFINITY, -INFINITY, -INFINITY, -INFINITY};
#pragma unroll 7
    for (int r = 0; r < 49; ++r) {
        f32x4 vv = __builtin_nontemporal_load(base + (size_t)r * 192);
        mx.x = fmaxf(mx.x, vv.x);
        mx.y = fmaxf(mx.y, vv.y);
        mx.z = fmaxf(mx.z, vv.z);
        mx.w = fmaxf(mx.w, vv.w);
    }

    __shared__ f32x4 sm4[4][192];         // 12 KiB
    __shared__ float red[12][5];
    __shared__ int sIdx[2];

    sm4[chunk][col] = mx;
    __syncthreads();

    // each thread owns ONE d element of the combined max
    const float* smf = reinterpret_cast<const float*>(sm4);
    const float xmd = fmaxf(fmaxf(smf[0 * 768 + tid], smf[1 * 768 + tid]),
                            fmaxf(smf[2 * 768 + tid], smf[3 * 768 + tid]));

    // fused 5-value reduction: Σxm, Σxm², Σxm·lw·u, Σlw·u, Σlb·u
    const float lu = lw * ud;
    float a0 = xmd, a1 = xmd * xmd, a2 = xmd * lu, a3 = lu, a4 = lb * ud;
#pragma unroll
    for (int off = 32; off; off >>= 1) {
        a0 += __shfl_down(a0, off);
        a1 += __shfl_down(a1, off);
        a2 += __shfl_down(a2, off);
        a3 += __shfl_down(a3, off);
        a4 += __shfl_down(a4, off);
    }
    const int wave = tid >> 6;
    if ((tid & 63) == 0) {
        red[wave][0] = a0; red[wave][1] = a1; red[wave][2] = a2;
        red[wave][3] = a3; red[wave][4] = a4;
    }
    __syncthreads();

    if (tid == 0) {
        float S0 = 0.f, S1 = 0.f, S2 = 0.f, S3 = 0.f, S4 = 0.f;
#pragma unroll
        for (int w = 0; w < 12; ++w) {
            S0 += red[w][0]; S1 += red[w][1]; S2 += red[w][2];
            S3 += red[w][3]; S4 += red[w][4];
        }
        const float mu   = S0 * (1.0f / 768.0f);
        const float var  = S1 * (1.0f / 768.0f) - mu * mu;
        const float rstd = 1.0f / sqrtf(var + 768.0f);   // EPS = 768.0
        t[bg] = rstd * (S2 - mu * S3) + S4;

        // signal + wait for the 7 sibling groups of this batch
        __hip_atomic_fetch_add(&done[b], 1, __ATOMIC_ACQ_REL, SCOPE_AGENT);
        while (__hip_atomic_load(&done[b], __ATOMIC_ACQUIRE, SCOPE_AGENT) < 8)
            __builtin_amdgcn_s_sleep(1);

        // top-2 of the 8 scores; jax.lax.top_k tie-break = lower index first
        float tv[8];
#pragma unroll
        for (int gi = 0; gi < 8; ++gi)
            tv[gi] = __hip_atomic_load(&t[b * 8 + gi], __ATOMIC_RELAXED, SCOPE_AGENT);
        float best = tv[0];
        int i0 = 0;
#pragma unroll
        for (int gi = 1; gi < 8; ++gi)
            if (tv[gi] > best) { best = tv[gi]; i0 = gi; }
        float best2 = -INFINITY;
        int i1 = 0;
#pragma unroll
        for (int gi = 0; gi < 8; ++gi) {
            if (gi == i0) continue;
            if (tv[gi] > best2) { best2 = tv[gi]; i1 = gi; }
        }
        sIdx[0] = i0;
        sIdx[1] = i1;
    }
    __syncthreads();
    const int i0 = sIdx[0], i1 = sIdx[1];

    // ---- gather output rows [g*50, min(g*50+50, 393)) of batch b ----
    const int obase = g * 50;
    const int nrows = min(50, 393 - obase);
    const int rsub = tid / 192;           // 0..3

    const f32x4* src_b = reinterpret_cast<const f32x4*>(inp) + (size_t)b * 1569 * 192;
    f32x4* dst_b = reinterpret_cast<f32x4*>(out) + (size_t)b * 393 * 192;

    auto src_of = [&](int it) -> const f32x4* {
        const int row = obase + rsub + 4 * it;
        int src_row;
        if (row == 0) {
            src_row = 0;                  // cls token
        } else {
            const int q = row - 1;        // 0..391
            const int gsel = (q < 196) ? i0 : i1;
            const int r = (q < 196) ? q : q - 196;
            src_row = 1 + gsel * 196 + r;
        }
        return src_b + (size_t)src_row * 192 + col;
    };

    const int nit = (nrows - rsub + 3) >> 2;   // rows handled by this thread
    f32x4 cur = __builtin_nontemporal_load(src_of(0));
    for (int it = 0; it < nit; ++it) {
        f32x4 nxt;
        if (it + 1 < nit) nxt = __builtin_nontemporal_load(src_of(it + 1));
        const int row = obase + rsub + 4 * it;
        __builtin_nontemporal_store(cur, dst_b + (size_t)row * 192 + col);
        cur = nxt;
    }
}

extern "C" void kernel_launch(void* const* d_in, const int* in_sizes, int n_in,
                              void* d_out, int out_size, void* d_ws, size_t ws_size,
                              hipStream_t stream) {
    const float* x    = (const float*)d_in[0];
    const float* inp  = (const float*)d_in[1];
    const float* ln_w = (const float*)d_in[2];
    const float* ln_b = (const float*)d_in[3];
    const float* w1   = (const float*)d_in[4];
    const float* w2   = (const float*)d_in[5];
    const float* w3   = (const float*)d_in[6];
    const float* w4   = (const float*)d_in[7];
    float* out = (float*)d_out;

    float* ws = (float*)d_ws;
    float* v = ws;            // 384 f32 used
    float* p = ws + 768;      // 768 f32
    float* u = ws + 1536;     // 768 f32
    float* t = ws + 2304;     // 512 f32
    int* bar  = (int*)(ws + 2816);   // bar[0..1], done[0..63]
    int* done = bar + 2;

    // zero the sync counters each call (capturable, deterministic)
    hipMemsetAsync(bar, 0, 66 * sizeof(int), stream);

    k_gemv_chain<<<dim3(64), dim3(256), 0, stream>>>(w3, w4, w2, w1, v, p, u, bar);
    k_stream_gather<<<dim3(512), dim3(768), 0, stream>>>(x, inp, ln_w, ln_b, u, t,
                                                         done, out);
}

// Round 8
// 130.771 us; speedup vs baseline: 1.0039x; 1.0039x over previous
//
#include <hip/hip_runtime.h>
#include <math.h>

// Problem: B=64, N=1568, D=768, groups=8, rows/group=196, T=1568.
// Output (B, 393, 768) f32 = [cls row | 196 rows of group i0 | 196 rows of group i1].
//
// Reduction: top_k ranking depends only on t[b,g] = xn[b,g] . u,
// u = w1 @ (w2 @ (w3@w4)[0:384]).  (x_a term constant per batch; min-max
// normalization monotone.)  Output is then a pure gather of inp rows.
//
// Structure (3 graph nodes):
//   memset(counters) -> k_gemv_chain (64 blocks, 2 internal barriers)
//                    -> k_stream_gather (512 blocks, per-batch done[] release)
//
// NOTE: no min-waves force on k_stream_gather. Round 6's __launch_bounds__(768,6)
// capped VGPRs at ~80 and spilled the streaming pipeline to scratch (+40us).

typedef float f32x4 __attribute__((ext_vector_type(4)));
typedef float f32x2 __attribute__((ext_vector_type(2)));

#define SCOPE_AGENT __HIP_MEMORY_SCOPE_AGENT

// ---------------- kernel 1: fused GEMV chain v -> p -> u ----------------
// 64 blocks x 256 threads (4 waves each; all co-resident on 256 CUs).
// bar[0], bar[1] are zeroed by the preceding memset each call.
__global__ __launch_bounds__(256) void k_gemv_chain(
    const float* __restrict__ w3, const float* __restrict__ w4,
    const float* __restrict__ w2, const float* __restrict__ w1,
    float* __restrict__ v, float* __restrict__ p, float* __restrict__ u,
    int* __restrict__ bar)
{
    const int tid = threadIdx.x;
    const int gw = blockIdx.x * 4 + (tid >> 6);   // global wave 0..255
    const int lane = tid & 63;

    // ---- stage 1: v[r] = w3[r, 0:768] . w4, r in [0, 384) ----
    {
        const f32x4* b4 = reinterpret_cast<const f32x4*>(w4);
        for (int r = gw; r < 384; r += 256) {
            const f32x4* a4 = reinterpret_cast<const f32x4*>(w3 + (size_t)r * 768);
            float s = 0.f;
#pragma unroll
            for (int i = 0; i < 3; ++i) {
                f32x4 a = a4[lane + 64 * i];
                f32x4 b = b4[lane + 64 * i];
                s += a.x * b.x + a.y * b.y + a.z * b.z + a.w * b.w;
            }
#pragma unroll
            for (int off = 32; off; off >>= 1) s += __shfl_down(s, off);
            if (lane == 0) v[r] = s;
        }
    }
    __syncthreads();
    if (tid == 0) {
        __hip_atomic_fetch_add(&bar[0], 1, __ATOMIC_ACQ_REL, SCOPE_AGENT);
        while (__hip_atomic_load(&bar[0], __ATOMIC_ACQUIRE, SCOPE_AGENT) < 64)
            __builtin_amdgcn_s_sleep(1);
    }
    __syncthreads();

    // ---- stage 2: p[r] = w2[r, 0:384] . v, r in [0, 768) ----
    {
        const f32x2* b2 = reinterpret_cast<const f32x2*>(v);
        for (int r = gw; r < 768; r += 256) {
            const f32x2* a2 = reinterpret_cast<const f32x2*>(w2 + (size_t)r * 384);
            float s = 0.f;
#pragma unroll
            for (int i = 0; i < 3; ++i) {
                f32x2 a = a2[lane + 64 * i];
                f32x2 b = b2[lane + 64 * i];
                s += a.x * b.x + a.y * b.y;
            }
#pragma unroll
            for (int off = 32; off; off >>= 1) s += __shfl_down(s, off);
            if (lane == 0) p[r] = s;
        }
    }
    __syncthreads();
    if (tid == 0) {
        __hip_atomic_fetch_add(&bar[1], 1, __ATOMIC_ACQ_REL, SCOPE_AGENT);
        while (__hip_atomic_load(&bar[1], __ATOMIC_ACQUIRE, SCOPE_AGENT) < 64)
            __builtin_amdgcn_s_sleep(1);
    }
    __syncthreads();

    // ---- stage 3: u[r] = w1[r, 0:768] . p, r in [0, 768) ----
    {
        const f32x4* b4 = reinterpret_cast<const f32x4*>(p);
        for (int r = gw; r < 768; r += 256) {
            const f32x4* a4 = reinterpret_cast<const f32x4*>(w1 + (size_t)r * 768);
            float s = 0.f;
#pragma unroll
            for (int i = 0; i < 3; ++i) {
                f32x4 a = a4[lane + 64 * i];
                f32x4 b = b4[lane + 64 * i];
                s += a.x * b.x + a.y * b.y + a.z * b.z + a.w * b.w;
            }
#pragma unroll
            for (int off = 32; off; off >>= 1) s += __shfl_down(s, off);
            if (lane == 0) u[r] = s;
        }
    }
}

// ---------------- kernel 2: fused max+LN+score -> per-batch gather ----------------
// 512 blocks x 768 threads, one (b,g) per block.  After writing t[b,g], block
// release-adds done[b]; spins until done[b]==8 (siblings are contiguous block
// ids -> co-resident under in-order dispatch at any occupancy).  Then gathers
// output chunk g of batch b.  NO min-waves force (VGPR-spill lesson, round 6).
__global__ __launch_bounds__(768) void k_stream_gather(
    const float* __restrict__ x, const float* __restrict__ inp,
    const float* __restrict__ ln_w, const float* __restrict__ ln_b,
    const float* __restrict__ u, float* __restrict__ t,
    int* __restrict__ done, float* __restrict__ out)
{
    const int bg = blockIdx.x;            // 0..511
    const int b = bg >> 3;
    const int g = bg & 7;
    const int tid = threadIdx.x;          // 0..767
    const int col = tid % 192;            // float4 column
    const int chunk = tid / 192;          // 0..3, 49 rows each

    // hoist parameter loads above the streaming loop (L2-hot after k1)
    const float lw = ln_w[tid];
    const float lb = ln_b[tid];
    const float ud = u[tid];

    const f32x4* base = reinterpret_cast<const f32x4*>(
        x + ((size_t)b * 1568 + (size_t)g * 196 + (size_t)chunk * 49) * 768) + col;

    f32x4 mx = {-INFINITY, -INFINITY, -INFINITY, -INFINITY};
#pragma unroll 7
    for (int r = 0; r < 49; ++r) {
        f32x4 vv = __builtin_nontemporal_load(base + (size_t)r * 192);
        mx.x = fmaxf(mx.x, vv.x);
        mx.y = fmaxf(mx.y, vv.y);
        mx.z = fmaxf(mx.z, vv.z);
        mx.w = fmaxf(mx.w, vv.w);
    }

    __shared__ f32x4 sm4[4][192];         // 12 KiB
    __shared__ float red[12][5];
    __shared__ int sIdx[2];

    sm4[chunk][col] = mx;
    __syncthreads();

    // each thread owns ONE d element of the combined max
    const float* smf = reinterpret_cast<const float*>(sm4);
    const float xmd = fmaxf(fmaxf(smf[0 * 768 + tid], smf[1 * 768 + tid]),
                            fmaxf(smf[2 * 768 + tid], smf[3 * 768 + tid]));

    // fused 5-value reduction: Σxm, Σxm², Σxm·lw·u, Σlw·u, Σlb·u
    const float lu = lw * ud;
    float a0 = xmd, a1 = xmd * xmd, a2 = xmd * lu, a3 = lu, a4 = lb * ud;
#pragma unroll
    for (int off = 32; off; off >>= 1) {
        a0 += __shfl_down(a0, off);
        a1 += __shfl_down(a1, off);
        a2 += __shfl_down(a2, off);
        a3 += __shfl_down(a3, off);
        a4 += __shfl_down(a4, off);
    }
    const int wave = tid >> 6;
    if ((tid & 63) == 0) {
        red[wave][0] = a0; red[wave][1] = a1; red[wave][2] = a2;
        red[wave][3] = a3; red[wave][4] = a4;
    }
    __syncthreads();

    if (tid == 0) {
        float S0 = 0.f, S1 = 0.f, S2 = 0.f, S3 = 0.f, S4 = 0.f;
#pragma unroll
        for (int w = 0; w < 12; ++w) {
            S0 += red[w][0]; S1 += red[w][1]; S2 += red[w][2];
            S3 += red[w][3]; S4 += red[w][4];
        }
        const float mu   = S0 * (1.0f / 768.0f);
        const float var  = S1 * (1.0f / 768.0f) - mu * mu;
        const float rstd = 1.0f / sqrtf(var + 768.0f);   // EPS = 768.0
        t[bg] = rstd * (S2 - mu * S3) + S4;

        // signal + wait for the 7 sibling groups of this batch
        __hip_atomic_fetch_add(&done[b], 1, __ATOMIC_ACQ_REL, SCOPE_AGENT);
        while (__hip_atomic_load(&done[b], __ATOMIC_ACQUIRE, SCOPE_AGENT) < 8)
            __builtin_amdgcn_s_sleep(1);

        // top-2 of the 8 scores; jax.lax.top_k tie-break = lower index first
        float tv[8];
#pragma unroll
        for (int gi = 0; gi < 8; ++gi)
            tv[gi] = __hip_atomic_load(&t[b * 8 + gi], __ATOMIC_RELAXED, SCOPE_AGENT);
        float best = tv[0];
        int i0 = 0;
#pragma unroll
        for (int gi = 1; gi < 8; ++gi)
            if (tv[gi] > best) { best = tv[gi]; i0 = gi; }
        float best2 = -INFINITY;
        int i1 = 0;
#pragma unroll
        for (int gi = 0; gi < 8; ++gi) {
            if (gi == i0) continue;
            if (tv[gi] > best2) { best2 = tv[gi]; i1 = gi; }
        }
        sIdx[0] = i0;
        sIdx[1] = i1;
    }
    __syncthreads();
    const int i0 = sIdx[0], i1 = sIdx[1];

    // ---- gather output rows [g*50, min(g*50+50, 393)) of batch b ----
    const int obase = g * 50;
    const int nrows = min(50, 393 - obase);
    const int rsub = tid / 192;           // 0..3

    const f32x4* src_b = reinterpret_cast<const f32x4*>(inp) + (size_t)b * 1569 * 192;
    f32x4* dst_b = reinterpret_cast<f32x4*>(out) + (size_t)b * 393 * 192;

    auto src_of = [&](int it) -> const f32x4* {
        const int row = obase + rsub + 4 * it;
        int src_row;
        if (row == 0) {
            src_row = 0;                  // cls token
        } else {
            const int q = row - 1;        // 0..391
            const int gsel = (q < 196) ? i0 : i1;
            const int r = (q < 196) ? q : q - 196;
            src_row = 1 + gsel * 196 + r;
        }
        return src_b + (size_t)src_row * 192 + col;
    };

    const int nit = (nrows - rsub + 3) >> 2;   // rows handled by this thread
    f32x4 cur = __builtin_nontemporal_load(src_of(0));
    for (int it = 0; it < nit; ++it) {
        f32x4 nxt;
        if (it + 1 < nit) nxt = __builtin_nontemporal_load(src_of(it + 1));
        const int row = obase + rsub + 4 * it;
        __builtin_nontemporal_store(cur, dst_b + (size_t)row * 192 + col);
        cur = nxt;
    }
}

extern "C" void kernel_launch(void* const* d_in, const int* in_sizes, int n_in,
                              void* d_out, int out_size, void* d_ws, size_t ws_size,
                              hipStream_t stream) {
    const float* x    = (const float*)d_in[0];
    const float* inp  = (const float*)d_in[1];
    const float* ln_w = (const float*)d_in[2];
    const float* ln_b = (const float*)d_in[3];
    const float* w1   = (const float*)d_in[4];
    const float* w2   = (const float*)d_in[5];
    const float* w3   = (const float*)d_in[6];
    const float* w4   = (const float*)d_in[7];
    float* out = (float*)d_out;

    float* ws = (float*)d_ws;
    float* v = ws;            // 384 f32 used
    float* p = ws + 768;      // 768 f32
    float* u = ws + 1536;     // 768 f32
    float* t = ws + 2304;     // 512 f32
    int* bar  = (int*)(ws + 2816);   // bar[0..1], done[0..63]
    int* done = bar + 2;

    // zero the sync counters each call (capturable, deterministic)
    hipMemsetAsync(bar, 0, 66 * sizeof(int), stream);

    k_gemv_chain<<<dim3(64), dim3(256), 0, stream>>>(w3, w4, w2, w1, v, p, u, bar);
    k_stream_gather<<<dim3(512), dim3(768), 0, stream>>>(x, inp, ln_w, ln_b, u, t,
                                                         done, out);
}

// Round 9
// 90.495 us; speedup vs baseline: 1.4507x; 1.4451x over previous
//
#include <hip/hip_runtime.h>
#include <hip/hip_bf16.h>
#include <math.h>

// Problem: B=64, N=1568, D=768, groups=8, rows/group=196, T=1568.
// Output (B, 393, 768) f32 = [cls row | 196 rows of group idx0 | 196 rows of group idx1].
//
// Reduction: top_k ranking depends only on t[b,g] = xn[b,g] . u,
// u = w1 @ (w2 @ (w3@w4)[0:384]).  (x_a term constant per batch; min-max
// normalization monotone.)  Output is then a pure gather of inp rows.
//
// Epilogue algebra (single reduction round):
//   t = rstd*(S2 - mu*S3) + S4, with S = Σ_d (xm, xm^2, xm*lw*u, lw*u, lb*u).
//
// NOTE (rounds 6-7): fusing the 5 kernels via agent-scope spin barriers
// regressed 90.7 -> 131 us (robust, launch-bounds-independent). Serial
// kernel structure is the fastest known; kept as-is.

typedef float f32x4 __attribute__((ext_vector_type(4)));
typedef float f32x2 __attribute__((ext_vector_type(2)));

// ---------------- GEMV kernels (one wave per row, 4 rows/block) ----------------
// rows of length 768 (used for v = w3@w4 [384 rows] and u = w1@p [768 rows])
__global__ __launch_bounds__(256) void k_gemv768(const float* __restrict__ M,
                                                 const float* __restrict__ vec,
                                                 float* __restrict__ outv) {
    const int wave = threadIdx.x >> 6;
    const int lane = threadIdx.x & 63;
    const int row = blockIdx.x * 4 + wave;
    const f32x4* r4 = reinterpret_cast<const f32x4*>(M + (size_t)row * 768);
    const f32x4* v4 = reinterpret_cast<const f32x4*>(vec);
    float s = 0.f;
#pragma unroll
    for (int i = 0; i < 3; ++i) {
        f32x4 a = r4[lane + 64 * i];
        f32x4 b = v4[lane + 64 * i];
        s += a.x * b.x + a.y * b.y + a.z * b.z + a.w * b.w;
    }
#pragma unroll
    for (int off = 32; off; off >>= 1) s += __shfl_down(s, off);
    if (lane == 0) outv[row] = s;
}

// rows of length 384 (p = w2 @ v_top, 768 rows)
__global__ __launch_bounds__(256) void k_gemv384(const float* __restrict__ M,
                                                 const float* __restrict__ vec,
                                                 float* __restrict__ outv) {
    const int wave = threadIdx.x >> 6;
    const int lane = threadIdx.x & 63;
    const int row = blockIdx.x * 4 + wave;
    const f32x2* r2 = reinterpret_cast<const f32x2*>(M + (size_t)row * 384);
    const f32x2* v2 = reinterpret_cast<const f32x2*>(vec);
    float s = 0.f;
#pragma unroll
    for (int i = 0; i < 3; ++i) {
        f32x2 a = r2[lane + 64 * i];
        f32x2 b = v2[lane + 64 * i];
        s += a.x * b.x + a.y * b.y;
    }
#pragma unroll
    for (int off = 32; off; off >>= 1) s += __shfl_down(s, off);
    if (lane == 0) outv[row] = s;
}

// ---------------- fused max-over-rows + layernorm + score ----------------
// One block per (b,g).  768 threads: col = tid%192 (float4 lane), chunk = tid/192
// handles 49 of the 196 rows.  Single fused 5-value reduction -> t[b*8+g].
__global__ __launch_bounds__(768) void k_max_score(const float* __restrict__ x,
                                                   const float* __restrict__ ln_w,
                                                   const float* __restrict__ ln_b,
                                                   const float* __restrict__ u,
                                                   float* __restrict__ t_out) {
    const int bg = blockIdx.x;            // 0..511
    const int b = bg >> 3;
    const int g = bg & 7;
    const int tid = threadIdx.x;          // 0..767
    const int col = tid % 192;            // float4 column
    const int chunk = tid / 192;          // 0..3, 49 rows each

    // hoist parameter loads above the streaming loop
    const float lw = ln_w[tid];
    const float lb = ln_b[tid];
    const float ud = u[tid];

    const f32x4* base = reinterpret_cast<const f32x4*>(
        x + ((size_t)b * 1568 + (size_t)g * 196 + (size_t)chunk * 49) * 768) + col;

    f32x4 mx = {-INFINITY, -INFINITY, -INFINITY, -INFINITY};
#pragma unroll 7
    for (int r = 0; r < 49; ++r) {
        f32x4 vv = __builtin_nontemporal_load(base + (size_t)r * 192);
        mx.x = fmaxf(mx.x, vv.x);
        mx.y = fmaxf(mx.y, vv.y);
        mx.z = fmaxf(mx.z, vv.z);
        mx.w = fmaxf(mx.w, vv.w);
    }

    __shared__ f32x4 sm4[4][192];         // 12 KiB
    __shared__ float red[12][5];

    sm4[chunk][col] = mx;
    __syncthreads();

    // each thread owns ONE d element of the combined max
    const float* smf = reinterpret_cast<const float*>(sm4);
    const float xmd = fmaxf(fmaxf(smf[0 * 768 + tid], smf[1 * 768 + tid]),
                            fmaxf(smf[2 * 768 + tid], smf[3 * 768 + tid]));

    // fused 5-value reduction: Σxm, Σxm², Σxm·lw·u, Σlw·u, Σlb·u
    const float lu = lw * ud;
    float a0 = xmd, a1 = xmd * xmd, a2 = xmd * lu, a3 = lu, a4 = lb * ud;
#pragma unroll
    for (int off = 32; off; off >>= 1) {
        a0 += __shfl_down(a0, off);
        a1 += __shfl_down(a1, off);
        a2 += __shfl_down(a2, off);
        a3 += __shfl_down(a3, off);
        a4 += __shfl_down(a4, off);
    }
    const int wave = tid >> 6;
    if ((tid & 63) == 0) {
        red[wave][0] = a0; red[wave][1] = a1; red[wave][2] = a2;
        red[wave][3] = a3; red[wave][4] = a4;
    }
    __syncthreads();
    if (tid == 0) {
        float S0 = 0.f, S1 = 0.f, S2 = 0.f, S3 = 0.f, S4 = 0.f;
#pragma unroll
        for (int w = 0; w < 12; ++w) {
            S0 += red[w][0]; S1 += red[w][1]; S2 += red[w][2];
            S3 += red[w][3]; S4 += red[w][4];
        }
        const float mu   = S0 * (1.0f / 768.0f);
        const float var  = S1 * (1.0f / 768.0f) - mu * mu;
        const float rstd = 1.0f / sqrtf(var + 768.0f);   // EPS = 768.0
        t_out[bg] = rstd * (S2 - mu * S3) + S4;
    }
}

// ---------------- top-2 select + gather ----------------
// grid (64, 8); block = 768 threads.  Block (b, chunk) copies rows
// [chunk*50, min(chunk*50+50, 393)).  Top-2 computed once, LDS broadcast.
// Load->store software-pipelined (one extra row load in flight).
__global__ __launch_bounds__(768) void k_gather(const float* __restrict__ inp,
                                                const float* __restrict__ t,
                                                float* __restrict__ out) {
    const int b = blockIdx.x;             // 0..63
    const int chunk = blockIdx.y;         // 0..7
    const int base = chunk * 50;
    const int nrows = min(50, 393 - base);
    const int tid = threadIdx.x;
    const int col = tid % 192;            // float4 column
    const int rsub = tid / 192;           // 0..3

    __shared__ int sIdx[2];
    if (tid == 0) {
        // top-2 of 8 scores; jax.lax.top_k tie-break = lower index first
        const float* tb = t + b * 8;
        float best = tb[0];
        int i0 = 0;
#pragma unroll
        for (int gi = 1; gi < 8; ++gi) {
            const float v = tb[gi];
            if (v > best) { best = v; i0 = gi; }
        }
        float best2 = -INFINITY;
        int i1 = 0;
#pragma unroll
        for (int gi = 0; gi < 8; ++gi) {
            if (gi == i0) continue;
            const float v = tb[gi];
            if (v > best2) { best2 = v; i1 = gi; }
        }
        sIdx[0] = i0;
        sIdx[1] = i1;
    }
    __syncthreads();
    const int i0 = sIdx[0], i1 = sIdx[1];

    const f32x4* src_b = reinterpret_cast<const f32x4*>(inp) + (size_t)b * 1569 * 192;
    f32x4* dst_b = reinterpret_cast<f32x4*>(out) + (size_t)b * 393 * 192;

    auto src_of = [&](int it) -> const f32x4* {
        const int row = base + rsub + 4 * it;
        int src_row;
        if (row == 0) {
            src_row = 0;                  // cls token
        } else {
            const int q = row - 1;        // 0..391
            const int gsel = (q < 196) ? i0 : i1;
            const int r = (q < 196) ? q : q - 196;
            src_row = 1 + gsel * 196 + r;
        }
        return src_b + (size_t)src_row * 192 + col;
    };

    const int nit = (nrows - rsub + 3) >> 2;   // rows handled by this thread
    f32x4 cur = __builtin_nontemporal_load(src_of(0));
    for (int it = 0; it < nit; ++it) {
        f32x4 nxt;
        if (it + 1 < nit) nxt = __builtin_nontemporal_load(src_of(it + 1));
        const int row = base + rsub + 4 * it;
        __builtin_nontemporal_store(cur, dst_b + (size_t)row * 192 + col);
        cur = nxt;
    }
}

extern "C" void kernel_launch(void* const* d_in, const int* in_sizes, int n_in,
                              void* d_out, int out_size, void* d_ws, size_t ws_size,
                              hipStream_t stream) {
    const float* x    = (const float*)d_in[0];
    const float* inp  = (const float*)d_in[1];
    const float* ln_w = (const float*)d_in[2];
    const float* ln_b = (const float*)d_in[3];
    const float* w1   = (const float*)d_in[4];
    const float* w2   = (const float*)d_in[5];
    const float* w3   = (const float*)d_in[6];
    const float* w4   = (const float*)d_in[7];
    float* out = (float*)d_out;

    float* ws = (float*)d_ws;
    float* v = ws;            // 384 f32 used (only v_top feeds w2)
    float* p = ws + 768;      // 768 f32
    float* u = ws + 1536;     // 768 f32
    float* t = ws + 2304;     // 512 f32  (all fully written before read)

    k_gemv768<<<dim3( 96), dim3(256), 0, stream>>>(w3, w4, v);   // v[0:384]
    k_gemv384<<<dim3(192), dim3(256), 0, stream>>>(w2, v, p);    // p[0:768]
    k_gemv768<<<dim3(192), dim3(256), 0, stream>>>(w1, p, u);    // u[0:768]
    k_max_score<<<dim3(512), dim3(768), 0, stream>>>(x, ln_w, ln_b, u, t);
    k_gather  <<<dim3(64, 8), dim3(768), 0, stream>>>(inp, t, out);
}